// Round 1
// baseline (244.512 us; speedup 1.0000x reference)
//
#include <hip/hip_runtime.h>

// out[n][p][m] = sum_c x[n][c][p] * rm[n][c][m]
// N=16, C=64, P=65536 (H*W), M=128.  Memory-bound: 256MB read + 512MB write.
// bf16 MFMA (16x16x32), fp32 accumulate. Inputs converted fp32->bf16 (RNE)
// during LDS staging.

#define NB   16
#define CDIM 64
#define PDIM 65536
#define MDIM 128
#define PT   128          // pixels per tile
#define BLOCKS_PER_N 64
#define TILES_PER_BLOCK 8 // (PDIM/PT)/BLOCKS_PER_N

typedef __attribute__((ext_vector_type(8))) short bf16x8;
typedef __attribute__((ext_vector_type(4))) float f32x4;

__device__ __forceinline__ unsigned short f2bf(float f) {
  union { float f; unsigned int u; } v; v.f = f;
  unsigned int u = v.u;
  u += 0x7fffu + ((u >> 16) & 1u);  // round-to-nearest-even
  return (unsigned short)(u >> 16);
}

// Element index into a [row][64] bf16 row-major LDS tile with 16B-slot XOR
// swizzle: row stride = 128B = 8 slots; slot ^= row&7 spreads stride-128B
// column reads across all 32 banks (G4).
__device__ __forceinline__ int swz(int row, int col) {
  int slot = (col >> 3) ^ (row & 7);
  return row * 64 + slot * 8 + (col & 7);
}

__global__ __launch_bounds__(256) void nlsa_kernel(
    const float* __restrict__ x, const float* __restrict__ rm,
    float* __restrict__ out) {
  __shared__ unsigned short lds_rm[MDIM * CDIM];  // [m][c] bf16 swizzled, 16KB
  __shared__ unsigned short lds_x[PT * CDIM];     // [p][c] bf16 swizzled, 16KB

  const int t = threadIdx.x;
  const int b = blockIdx.x;
  const int n  = b >> 6;            // 64 blocks per batch element
  const int bt = b & 63;

  const float* xn  = x  + (size_t)n * CDIM * PDIM;
  const float* rmn = rm + (size_t)n * CDIM * MDIM;
  float*       outn = out + (size_t)n * PDIM * MDIM;

  // ---- stage rm[n] (64c x 128m fp32) -> lds_rm[m][c] bf16, once per block
  {
    const int m  = t & 127;
    const int cb = (t >> 7) * 4;    // thread-half picks c mod 8 range
    for (int it = 0; it < 8; ++it) {
      const int c0 = cb + it * 8;
      ushort4 v;
      v.x = f2bf(rmn[(c0 + 0) * MDIM + m]);
      v.y = f2bf(rmn[(c0 + 1) * MDIM + m]);
      v.z = f2bf(rmn[(c0 + 2) * MDIM + m]);
      v.w = f2bf(rmn[(c0 + 3) * MDIM + m]);
      *(ushort4*)&lds_rm[swz(m, c0)] = v;
    }
  }
  __syncthreads();

  const int w  = t >> 6;    // wave id 0..3: owns m range [32w, 32w+32)
  const int l  = t & 63;
  const int lo = l & 15;
  const int g  = l >> 4;

  // ---- A fragments (rm) held in registers for the whole block
  // A[row=m][k=c]: lane holds rows m0+(l&15), k = ks*32 + 8*(l>>4) + i
  bf16x8 a[2][2];
#pragma unroll
  for (int mt = 0; mt < 2; ++mt)
#pragma unroll
    for (int ks = 0; ks < 2; ++ks)
      a[mt][ks] = *(const bf16x8*)&lds_rm[swz(w * 32 + mt * 16 + lo,
                                              ks * 32 + g * 8)];

  for (int k = 0; k < TILES_PER_BLOCK; ++k) {
    const int p_base = (bt + k * BLOCKS_PER_N) * PT;

    __syncthreads();  // protect lds_x against previous iteration's readers
    // ---- stage x tile (64c x 128p fp32) -> lds_x[p][c] bf16
    {
      const int p  = t & 127;
      const int cb = (t >> 7) * 4;
      const float* xp = xn + p_base + p;
      for (int it = 0; it < 8; ++it) {
        const int c0 = cb + it * 8;
        ushort4 v;
        v.x = f2bf(xp[(size_t)(c0 + 0) * PDIM]);
        v.y = f2bf(xp[(size_t)(c0 + 1) * PDIM]);
        v.z = f2bf(xp[(size_t)(c0 + 2) * PDIM]);
        v.w = f2bf(xp[(size_t)(c0 + 3) * PDIM]);
        *(ushort4*)&lds_x[swz(p, c0)] = v;
      }
    }
    __syncthreads();

    // ---- compute: D[m][p] tiles; lane's f32x4 = 4 consecutive m at one p
#pragma unroll
    for (int pt = 0; pt < 8; ++pt) {
      bf16x8 b0 = *(const bf16x8*)&lds_x[swz(pt * 16 + lo,      g * 8)];
      bf16x8 b1 = *(const bf16x8*)&lds_x[swz(pt * 16 + lo, 32 + g * 8)];
      f32x4 acc0 = {0.f, 0.f, 0.f, 0.f};
      f32x4 acc1 = {0.f, 0.f, 0.f, 0.f};
      acc0 = __builtin_amdgcn_mfma_f32_16x16x32_bf16(a[0][0], b0, acc0, 0, 0, 0);
      acc0 = __builtin_amdgcn_mfma_f32_16x16x32_bf16(a[0][1], b1, acc0, 0, 0, 0);
      acc1 = __builtin_amdgcn_mfma_f32_16x16x32_bf16(a[1][0], b0, acc1, 0, 0, 0);
      acc1 = __builtin_amdgcn_mfma_f32_16x16x32_bf16(a[1][1], b1, acc1, 0, 0, 0);

      const int p = p_base + pt * 16 + lo;
      float* dst = outn + (size_t)p * MDIM + w * 32 + g * 4;
      *(f32x4*)(dst)      = acc0;   // m = 32w + 4g + {0..3}
      *(f32x4*)(dst + 16) = acc1;   // m = 32w + 16 + 4g + {0..3}
    }
  }
}

extern "C" void kernel_launch(void* const* d_in, const int* in_sizes, int n_in,
                              void* d_out, int out_size, void* d_ws, size_t ws_size,
                              hipStream_t stream) {
  const float* x  = (const float*)d_in[0];   // (N, C, H, W) fp32
  const float* rm = (const float*)d_in[1];   // (N, C, M) fp32
  float* out = (float*)d_out;                // (N, P, M) fp32
  nlsa_kernel<<<dim3(NB * BLOCKS_PER_N), dim3(256), 0, stream>>>(x, rm, out);
}

// Round 2
// 161.712 us; speedup vs baseline: 1.5120x; 1.5120x over previous
//
#include <hip/hip_runtime.h>

// out[n][p][m] = sum_c x[n][c][p] * rm[n][c][m]
// N=16, C=64, P=65536, M=128. Memory-bound: 256MB read + 512MB write -> floor ~122us.
// v2: float4 coalesced x reads + [c][p] LDS (transpose via ds_read_u16 gather),
//     raw s_barrier with lgkm-only waits (no store-queue drain), reg prefetch.

#define NB   16
#define CDIM 64
#define PDIM 65536
#define MDIM 128
#define PT   128
#define BLOCKS_PER_N 64
#define TILES_PER_BLOCK 8
#define XS   132   // lds_x row stride (bf16): mult-of-4 keeps 8B-aligned writes;
                   // 132*2=264B rows -> gather banks spread (~2-way, free per m136)

typedef __attribute__((ext_vector_type(8))) short bf16x8;
typedef __attribute__((ext_vector_type(4))) float f32x4;

__device__ __forceinline__ unsigned short f2bf(float f) {
  union { float f; unsigned int u; } v; v.f = f;
  unsigned int u = v.u;
  u += 0x7fffu + ((u >> 16) & 1u);  // RNE
  return (unsigned short)(u >> 16);
}

// rm tile swizzle (unchanged from v1, verified): [m][64c] bf16, 16B-slot XOR
__device__ __forceinline__ int swz(int row, int col) {
  int slot = (col >> 3) ^ (row & 7);
  return row * 64 + slot * 8 + (col & 7);
}

__global__ __launch_bounds__(256, 4) void nlsa_kernel(
    const float* __restrict__ x, const float* __restrict__ rm,
    float* __restrict__ out) {
  __shared__ unsigned short lds_rm[MDIM * CDIM];  // 16KB
  __shared__ unsigned short lds_x[CDIM * XS];     // 16.5KB  (total 33KB -> 4 blocks/CU)

  const int t = threadIdx.x;
  const int b = blockIdx.x;
  const int n  = b >> 6;
  const int bt = b & 63;

  const float* xn   = x  + (size_t)n * CDIM * PDIM;
  const float* rmn  = rm + (size_t)n * CDIM * MDIM;
  float*       outn = out + (size_t)n * PDIM * MDIM;

  // x staging map: thread t loads float4 at (c = cst+8*it, p = pst..pst+3).
  // Per wave-instr: 2 c-rows x 512B contiguous global, 8B contiguous LDS writes.
  const int cst = t >> 5;          // 0..7
  const int pst = (t & 31) * 4;    // 0..124

  float4 r[8];
  // issue tile-0 loads first so they fly under rm staging
  {
    const float* src = xn + (size_t)(bt * PT + pst);
#pragma unroll
    for (int it = 0; it < 8; ++it)
      r[it] = *(const float4*)(src + (size_t)(cst + it * 8) * PDIM);
  }

  // ---- stage rm[n] -> lds_rm[m][c] bf16 (once per block)
  {
    const int m  = t & 127;
    const int cb = (t >> 7) * 4;
#pragma unroll
    for (int it = 0; it < 8; ++it) {
      const int c0 = cb + it * 8;
      ushort4 v;
      v.x = f2bf(rmn[(c0 + 0) * MDIM + m]);
      v.y = f2bf(rmn[(c0 + 1) * MDIM + m]);
      v.z = f2bf(rmn[(c0 + 2) * MDIM + m]);
      v.w = f2bf(rmn[(c0 + 3) * MDIM + m]);
      *(ushort4*)&lds_rm[swz(m, c0)] = v;
    }
  }
  __syncthreads();  // once; also covers tile-0 loads ordering harmlessly

  const int w  = t >> 6;    // wave: m range [32w, 32w+32)
  const int l  = t & 63;
  const int lo = l & 15;
  const int g  = l >> 4;

  // A fragments (rm) in registers for the whole kernel
  bf16x8 a[2][2];
#pragma unroll
  for (int mt = 0; mt < 2; ++mt)
#pragma unroll
    for (int ks = 0; ks < 2; ++ks)
      a[mt][ks] = *(const bf16x8*)&lds_rm[swz(w * 32 + mt * 16 + lo,
                                              ks * 32 + g * 8)];

  for (int k = 0; k < TILES_PER_BLOCK; ++k) {
    // barrier1: all waves done READING lds_x for tile k-1 (reads are consumed
    // pre-barrier, so no waitcnt needed) -- raw barrier, no vmcnt(0) drain.
    asm volatile("" ::: "memory");
    __builtin_amdgcn_s_barrier();
    asm volatile("" ::: "memory");

    // write staged tile into lds_x[c][p] (compiler inserts counted vmcnt for r)
#pragma unroll
    for (int it = 0; it < 8; ++it) {
      ushort4 v;
      v.x = f2bf(r[it].x); v.y = f2bf(r[it].y);
      v.z = f2bf(r[it].z); v.w = f2bf(r[it].w);
      *(ushort4*)&lds_x[(cst + it * 8) * XS + pst] = v;
    }

    // prefetch tile k+1 into r (overlaps the whole compute phase below)
    if (k + 1 < TILES_PER_BLOCK) {
      const float* src = xn + (size_t)((bt + (k + 1) * BLOCKS_PER_N) * PT + pst);
#pragma unroll
      for (int it = 0; it < 8; ++it)
        r[it] = *(const float4*)(src + (size_t)(cst + it * 8) * PDIM);
    }

    // barrier2: lds_x writes visible; lgkm-only wait (store queue NOT drained)
    asm volatile("s_waitcnt lgkmcnt(0)" ::: "memory");
    __builtin_amdgcn_s_barrier();
    asm volatile("" ::: "memory");

    const int p_base = (bt + k * BLOCKS_PER_N) * PT;
#pragma unroll
    for (int pt_ = 0; pt_ < 8; ++pt_) {
      const int pl = pt_ * 16 + lo;
      // B fragments: 8-c gather at one p from [c][p] layout (2B reads, ~2-way banks)
      bf16x8 b0, b1;
#pragma unroll
      for (int i = 0; i < 8; ++i) {
        b0[i] = (short)lds_x[(g * 8 + i) * XS + pl];
        b1[i] = (short)lds_x[(32 + g * 8 + i) * XS + pl];
      }
      f32x4 acc0 = {0.f, 0.f, 0.f, 0.f};
      f32x4 acc1 = {0.f, 0.f, 0.f, 0.f};
      acc0 = __builtin_amdgcn_mfma_f32_16x16x32_bf16(a[0][0], b0, acc0, 0, 0, 0);
      acc0 = __builtin_amdgcn_mfma_f32_16x16x32_bf16(a[0][1], b1, acc0, 0, 0, 0);
      acc1 = __builtin_amdgcn_mfma_f32_16x16x32_bf16(a[1][0], b0, acc1, 0, 0, 0);
      acc1 = __builtin_amdgcn_mfma_f32_16x16x32_bf16(a[1][1], b1, acc1, 0, 0, 0);

      float* dst = outn + (size_t)(p_base + pl) * MDIM + w * 32 + g * 4;
      *(f32x4*)(dst)      = acc0;   // m = 32w + 4g + {0..3}
      *(f32x4*)(dst + 16) = acc1;   // m = 32w + 16 + 4g + {0..3}
    }
  }
}

extern "C" void kernel_launch(void* const* d_in, const int* in_sizes, int n_in,
                              void* d_out, int out_size, void* d_ws, size_t ws_size,
                              hipStream_t stream) {
  const float* x  = (const float*)d_in[0];   // (N, C, H, W) fp32
  const float* rm = (const float*)d_in[1];   // (N, C, M) fp32
  float* out = (float*)d_out;                // (N, P, M) fp32
  nlsa_kernel<<<dim3(NB * BLOCKS_PER_N), dim3(256), 0, stream>>>(x, rm, out);
}